// Round 5
// baseline (2137.923 us; speedup 1.0000x reference)
//
#include <hip/hip_runtime.h>
#include <math.h>

// ---------------------------------------------------------------------------
// TinyViT block on MI355X (gfx950). Internal compute bf16 MFMA + fp32 accum.
// Round-10: gemm_nt rewritten as 4-phase, BK=64, triple-buffered (m201-style
// adapted to BN=128). Evidence: r6/r7/r8 schedules (2-drain / 1-drain+dbuf /
// counted-vmcnt depth-2) ALL land 240-256us, MfmaUtil ~9%, occupancy ~26%,
// ~2 loads in flight/CU -> concurrency-starved lockstep; BK=32's 16 MFMA
// between barriers can't cover latency. New structure per K-tile (64):
//   vmcnt(12) [counted, never 0 mid-loop] ; barrier
//   4 x { ds_read 2-6 b128 ; setprio1 ; 8 MFMA ; setprio0 ; barrier }
//   barrier ; STAGE(t+3)   // depth-3: ~2 iters (~2000cy) of latency cover
// LDS 144KB (A 3x32KB + B 3x16KB), 1 block/CU, 8 waves 4Mx2N, wave=64x64.
// k-quad slot swizzle q^(r&7) (linear DMA dest + pre-swizzled src + swz read).
// 1-D grid with bijective XCD-chunked remap (m204): n-blocks sharing an
// A-panel land on one XCD L2 (FETCH was 1.7x A's bytes).
// attn (round-6 MFMA), dwconv (round-5), LN, transposes unchanged.
// ---------------------------------------------------------------------------

typedef __bf16 bf16x8 __attribute__((ext_vector_type(8)));
typedef float f32x4 __attribute__((ext_vector_type(4)));
typedef unsigned short u16x8 __attribute__((ext_vector_type(8)));

__device__ __forceinline__ float b2f(unsigned short u) {
    union { unsigned int i; float f; } x;
    x.i = ((unsigned int)u) << 16;
    return x.f;
}
__device__ __forceinline__ unsigned short f2b(float f) {
    union { float f; unsigned int i; } x;
    x.f = f;
    unsigned int i = x.i;
    return (unsigned short)((i + 0x7fffu + ((i >> 16) & 1u)) >> 16);
}
// element i of a dual-view buffer (fp32 view pf, bf16 view pb), per flag
__device__ __forceinline__ float rd2(const float* pf, const unsigned short* pb,
                                     long i, int f32) {
    return f32 ? pf[i] : b2f(pb[i]);
}

// ---------------------------------------------------------------------------
__global__ void detect_dtype(const unsigned int* __restrict__ gamma1,
                             int* __restrict__ flag)
{
    if (threadIdx.x == 0) flag[0] = (gamma1[0] == 0x3F800000u) ? 1 : 0;
}

// ---------------------------------------------------------------------------
// Convert all small params to one canonical bf16 buffer.
// layout (elems): g1 0 | b1 384 | bp 768 | g2 1152 | b2 1536 | bf1 1920
//                 | wdwT 3456 (k-major: [k][1536]) | bdw 17280 | bf2 18816
//                 | rb 19200 | end 20214
// ---------------------------------------------------------------------------
__global__ __launch_bounds__(256) void convert_smalls(
    const int* __restrict__ flag,
    const void* g1, const void* b1, const void* bp, const void* g2,
    const void* b2, const void* bf1, const void* wdw, const void* bdw,
    const void* bf2, const void* rb, unsigned short* __restrict__ dst)
{
    int i = blockIdx.x * 256 + threadIdx.x;
    if (i >= 20214) return;
    const int f = flag[0];
    const void* src; long j; int o = i;
    if      (i < 384)   { src = g1;  j = i; }
    else if (i < 768)   { src = b1;  j = i - 384; }
    else if (i < 1152)  { src = bp;  j = i - 768; }
    else if (i < 1536)  { src = g2;  j = i - 1152; }
    else if (i < 1920)  { src = b2;  j = i - 1536; }
    else if (i < 3456)  { src = bf1; j = i - 1920; }
    else if (i < 17280) {
        // destination index i-3456 = k*1536 + ch (k-major); source = ch*9 + k
        int d = i - 3456, k = d / 1536, ch = d % 1536;
        src = wdw; j = (long)ch * 9 + k;
    }
    else if (i < 18816) { src = bdw; j = i - 17280; }
    else if (i < 19200) { src = bf2; j = i - 18816; }
    else                { src = rb;  j = i - 19200; }
    float v = f ? ((const float*)src)[j] : b2f(((const unsigned short*)src)[j]);
    dst[o] = f2b(v);
}

// ---------------------------------------------------------------------------
// Flag-aware tiled transpose to bf16: out[c*R + r] = (bf16)in[r*C + c]
// ---------------------------------------------------------------------------
__global__ __launch_bounds__(256) void transpose_any(
    const void* __restrict__ in, unsigned short* __restrict__ out,
    int R, int C, const int* __restrict__ flag)
{
    __shared__ unsigned short tile[32][33];
    const int f = flag[0];
    int tx = threadIdx.x & 31, ty = threadIdx.x >> 5;
    int rb = blockIdx.y * 32, cb = blockIdx.x * 32;
#pragma unroll
    for (int i = 0; i < 32; i += 8) {
        int r = rb + ty + i, c = cb + tx;
        if (r < R && c < C)
            tile[ty + i][tx] = f2b(rd2((const float*)in,
                                       (const unsigned short*)in,
                                       (long)r * C + c, f));
    }
    __syncthreads();
#pragma unroll
    for (int i = 0; i < 32; i += 8) {
        int c = cb + ty + i, r = rb + tx;
        if (c < C && r < R) out[(long)c * R + r] = tile[tx][ty + i];
    }
}

// ---------------------------------------------------------------------------
// LayerNorm over C=384, one wave per token. Input = dual view (xf/xb) per
// flag; force_f32=1 -> always fp32 (flagp ignored). gamma/beta bf16.
// ---------------------------------------------------------------------------
__global__ __launch_bounds__(256) void ln_kernel(
    const float* __restrict__ xf, const unsigned short* __restrict__ xb,
    const unsigned short* __restrict__ gamma,
    const unsigned short* __restrict__ beta,
    unsigned short* __restrict__ yout, int T,
    const int* __restrict__ flagp, int force_f32)
{
    int w = blockIdx.x * 4 + (threadIdx.x >> 6);
    int lane = threadIdx.x & 63;
    if (w >= T) return;
    const int f32 = force_f32 ? 1 : flagp[0];
    long base = (long)w * 384;
    float v[6];
    float s = 0.f;
#pragma unroll
    for (int i = 0; i < 6; ++i) {
        v[i] = rd2(xf, xb, base + lane + i * 64, f32);
        s += v[i];
    }
#pragma unroll
    for (int o = 32; o > 0; o >>= 1) s += __shfl_xor(s, o);
    float mu = s * (1.f / 384.f);
    float q = 0.f;
#pragma unroll
    for (int i = 0; i < 6; ++i) { float d = v[i] - mu; q += d * d; }
#pragma unroll
    for (int o = 32; o > 0; o >>= 1) q += __shfl_xor(q, o);
    float rs = rsqrtf(q * (1.f / 384.f) + 1e-5f);
#pragma unroll
    for (int i = 0; i < 6; ++i) {
        int cc = lane + i * 64;
        yout[base + cc] = f2b((v[i] - mu) * rs * b2f(gamma[cc]) + b2f(beta[cc]));
    }
}

// ---------------------------------------------------------------------------
// GEMM: C[M,N] = A[M,K] * BT[N,K]^T, bf16 in, fp32 accum.
// EPI: 0=store, 1=+bias, 2=+bias+residual. Residual & output are dual-view
// (fp32 ptr + bf16 ptr); runtime flags may override the static dtype bools.
// N%128==0, K%64==0; M arbitrary (A-row clamp + store guard).
//
// Round-10 structure (see file header). 1-D grid: wgid -> (m,n) after
// bijective XCD-chunk remap. BM=256, BN=128, BK=64, 512 thr = 8 waves
// (4M x 2N), wave = 64x64 out via 4x4 16x16x32 tiles, acc math and C/D
// layout identical to the verified versions.
// LDS chunk map (per tile): row r (256 A / 128 B), k-quad q (0..7, 16B)
// stored at slot q ^ (r&7) -> chunk index r*8 + (q^(r&7)). DMA dest is
// lane-linear (c*16B); source address pre-swizzled; reads re-apply the XOR.
// ---------------------------------------------------------------------------
template<int EPI, bool OUT_F32_S, bool RES_F32_S>
__global__ __launch_bounds__(512) void gemm_nt(
    const unsigned short* __restrict__ A,
    const unsigned short* __restrict__ BT,
    float* __restrict__ Cf, unsigned short* __restrict__ Cb,
    const unsigned short* __restrict__ bias,
    const float* __restrict__ Rf, const unsigned short* __restrict__ Rb,
    int M, int N, int K,
    const int* __restrict__ rflagp, const int* __restrict__ oflagp)
{
    __shared__ __align__(16) unsigned short ldsA[3][256 * 64];   // 96 KB
    __shared__ __align__(16) unsigned short ldsB[3][128 * 64];   // 48 KB
    const int tid = threadIdx.x;               // 0..511
    const int lane = tid & 63;
    const int wv = tid >> 6;                   // 0..7
    const int waveM = wv >> 1, waveN = wv & 1; // 4 x 2 wave grid

    // ---- bijective XCD-chunked remap (m204): each XCD gets a contiguous
    // range of logical ids; logical order is n-fast so blocks sharing an
    // A-panel land on the same XCD's L2. ----
    const int nwg = (int)gridDim.x;
    const int orig = (int)blockIdx.x;
    const int qq = nwg >> 3, rr = nwg & 7, xcd = orig & 7;
    const int wgid = (xcd < rr ? xcd * (qq + 1)
                               : rr * (qq + 1) + (xcd - rr) * qq) + (orig >> 3);
    const int NB = N >> 7;                     // N/128 blocks in n
    const long m0 = (long)(wgid / NB) * 256;
    const long n0 = (long)(wgid % NB) * 128;

    f32x4 acc[4][4] = {};

    // ---- staging ownership: A = 2048 16B-chunks (4/thread), B = 1024
    // (2/thread). chunk c: row=c>>3, slot=c&7, global k-quad = slot^(row&7).
    const unsigned short* aptr[4];
    const unsigned short* bptr[2];
#pragma unroll
    for (int i = 0; i < 4; ++i) {
        int c = tid + i * 512, r = c >> 3, q = (c & 7) ^ (r & 7);
        long row = m0 + r; if (row >= M) row = M - 1;   // clamp (dup ok)
        aptr[i] = A + row * (long)K + q * 8;
    }
#pragma unroll
    for (int i = 0; i < 2; ++i) {
        int c = tid + i * 512, r = c >> 3, q = (c & 7) ^ (r & 7);
        bptr[i] = BT + (n0 + r) * (long)K + q * 8;
    }

    auto STAGE = [&](int buf, int kt) {
#pragma unroll
        for (int i = 0; i < 4; ++i)
            __builtin_amdgcn_global_load_lds(
                (const __attribute__((address_space(1))) void*)(aptr[i] + kt),
                (__attribute__((address_space(3))) void*)
                    (&ldsA[buf][(tid + i * 512) * 8]), 16, 0, 0);
#pragma unroll
        for (int i = 0; i < 2; ++i)
            __builtin_amdgcn_global_load_lds(
                (const __attribute__((address_space(1))) void*)(bptr[i] + kt),
                (__attribute__((address_space(3))) void*)
                    (&ldsB[buf][(tid + i * 512) * 8]), 16, 0, 0);
    };

    const int nt = K >> 6;                     // K/64 (384->6, 1536->24)
    // prologue: three tiles in flight (18 loads/wave max)
    STAGE(0, 0);
    if (nt > 1) STAGE(1, 64);
    if (nt > 2) STAGE(2, 128);

    const int rq = lane & 15, quad = lane >> 4;

    for (int t = 0; t < nt; ++t) {
        const int cur = t % 3;
        const unsigned short* As = ldsA[cur];
        const unsigned short* Bs = ldsB[cur];

        // (a) counted wait: tile t's 6 loads done; newer tiles stay in air
        const int rem = nt - 1 - t;
        if (rem >= 2)      asm volatile("s_waitcnt vmcnt(12)" ::: "memory");
        else if (rem == 1) asm volatile("s_waitcnt vmcnt(6)" ::: "memory");
        else               asm volatile("s_waitcnt vmcnt(0)" ::: "memory");
        __builtin_amdgcn_s_barrier();          // (b) tile t visible to all

        // fragment readers (k-quad kq = h*4+quad, slot re-XOR'd)
        auto LDA = [&](int mi, int h) {
            int R = waveM * 64 + mi * 16 + rq;
            int ch = R * 8 + ((h * 4 + quad) ^ (R & 7));
            return *(const bf16x8*)(As + ch * 8);
        };
        auto LDB = [&](int ni, int h) {
            int R = waveN * 64 + ni * 16 + rq;
            int ch = R * 8 + ((h * 4 + quad) ^ (R & 7));
            return *(const bf16x8*)(Bs + ch * 8);
        };

        bf16x8 b0, b1, b2, b3, a0, a1;
        // ---- phase 0: h=0, mi 0-1 ----
        b0 = LDB(0, 0); b1 = LDB(1, 0); b2 = LDB(2, 0); b3 = LDB(3, 0);
        a0 = LDA(0, 0); a1 = LDA(1, 0);
        __builtin_amdgcn_s_setprio(1);
        acc[0][0] = __builtin_amdgcn_mfma_f32_16x16x32_bf16(a0, b0, acc[0][0], 0, 0, 0);
        acc[0][1] = __builtin_amdgcn_mfma_f32_16x16x32_bf16(a0, b1, acc[0][1], 0, 0, 0);
        acc[0][2] = __builtin_amdgcn_mfma_f32_16x16x32_bf16(a0, b2, acc[0][2], 0, 0, 0);
        acc[0][3] = __builtin_amdgcn_mfma_f32_16x16x32_bf16(a0, b3, acc[0][3], 0, 0, 0);
        acc[1][0] = __builtin_amdgcn_mfma_f32_16x16x32_bf16(a1, b0, acc[1][0], 0, 0, 0);
        acc[1][1] = __builtin_amdgcn_mfma_f32_16x16x32_bf16(a1, b1, acc[1][1], 0, 0, 0);
        acc[1][2] = __builtin_amdgcn_mfma_f32_16x16x32_bf16(a1, b2, acc[1][2], 0, 0, 0);
        acc[1][3] = __builtin_amdgcn_mfma_f32_16x16x32_bf16(a1, b3, acc[1][3], 0, 0, 0);
        __builtin_amdgcn_s_setprio(0);
        __builtin_amdgcn_s_barrier();
        // ---- phase 1: h=0, mi 2-3 ----
        a0 = LDA(2, 0); a1 = LDA(3, 0);
        __builtin_amdgcn_s_setprio(1);
        acc[2][0] = __builtin_amdgcn_mfma_f32_16x16x32_bf16(a0, b0, acc[2][0], 0, 0, 0);
        acc[2][1] = __builtin_amdgcn_mfma_f32_16x16x32_bf16(a0, b1, acc[2][1], 0, 0, 0);
        acc[2][2] = __builtin_amdgcn_mfma_f32_16x16x32_bf16(a0, b2, acc[2][2], 0, 0, 0);
        acc[2][3] = __builtin_amdgcn_mfma_f32_16x16x32_bf16(a0, b3, acc[2][3], 0, 0, 0);
        acc[3][0] = __builtin_amdgcn_mfma_f32_16x16x32_bf16(a1, b0, acc[3][0], 0, 0, 0);
        acc[3][1] = __builtin_amdgcn_mfma_f32_16x16x32_bf16(a1, b1, acc[3][1], 0, 0, 0);
        acc[3][2] = __builtin_amdgcn_mfma_f32_16x16x32_bf16(a1, b2, acc[3][2], 0, 0, 0);
        acc[3][3] = __builtin_amdgcn_mfma_f32_16x16x32_bf16(a1, b3, acc[3][3], 0, 0, 0);
        __builtin_amdgcn_s_setprio(0);
        __builtin_amdgcn_s_barrier();
        // ---- phase 2: h=1, mi 0-1 ----
        b0 = LDB(0, 1); b1 = LDB(1, 1); b2 = LDB(2, 1); b3 = LDB(3, 1);
        a0 = LDA(0, 1); a1 = LDA(1, 1);
        __builtin_amdgcn_s_setprio(1);
        acc[0][0] = __builtin_amdgcn_mfma_f32_16x16x32_bf16(a0, b0, acc[0][0], 0, 0, 0);
        acc[0][1] = __builtin_amdgcn_mfma_f32_16x16x32_bf16(a0, b1, acc[0][1], 0, 0, 0);
        acc[0][2] = __builtin_amdgcn_mfma_f32_16x16x32_bf16(a0, b2, acc[0][2], 0, 0, 0);
        acc[0][3] = __builtin_amdgcn_mfma_f32_16x16x32_bf16(a0, b3, acc[0][3], 0, 0, 0);
        acc[1][0] = __builtin_amdgcn_mfma_f32_16x16x32_bf16(a1, b0, acc[1][0], 0, 0, 0);
        acc[1][1] = __builtin_amdgcn_mfma_f32_16x16x32_bf16(a1, b1, acc[1][1], 0, 0, 0);
        acc[1][2] = __builtin_amdgcn_mfma_f32_16x16x32_bf16(a1, b2, acc[1][2], 0, 0, 0);
        acc[1][3] = __builtin_amdgcn_mfma_f32_16x16x32_bf16(a1, b3, acc[1][3], 0, 0, 0);
        __builtin_amdgcn_s_setprio(0);
        __builtin_amdgcn_s_barrier();
        // ---- phase 3: h=1, mi 2-3 ----
        a0 = LDA(2, 1); a1 = LDA(3, 1);
        __builtin_amdgcn_s_setprio(1);
        acc[2][0] = __builtin_amdgcn_mfma_f32_16x16x32_bf16(a0, b0, acc[2][0], 0, 0, 0);
        acc[2][1] = __builtin_amdgcn_mfma_f32_16x16x32_bf16(a0, b1, acc[2][1], 0, 0, 0);
        acc[2][2] = __builtin_amdgcn_mfma_f32_16x16x32_bf16(a0, b2, acc[2][2], 0, 0, 0);
        acc[2][3] = __builtin_amdgcn_mfma_f32_16x16x32_bf16(a0, b3, acc[2][3], 0, 0, 0);
        acc[3][0] = __builtin_amdgcn_mfma_f32_16x16x32_bf16(a1, b0, acc[3][0], 0, 0, 0);
        acc[3][1] = __builtin_amdgcn_mfma_f32_16x16x32_bf16(a1, b1, acc[3][1], 0, 0, 0);
        acc[3][2] = __builtin_amdgcn_mfma_f32_16x16x32_bf16(a1, b2, acc[3][2], 0, 0, 0);
        acc[3][3] = __builtin_amdgcn_mfma_f32_16x16x32_bf16(a1, b3, acc[3][3], 0, 0, 0);
        __builtin_amdgcn_s_setprio(0);

        __builtin_amdgcn_s_barrier();          // (d) all reads of buf done
        if (t + 3 < nt) STAGE(cur, (t + 3) * 64);   // (e) refill -> depth 3
    }

    const int res_f32 = rflagp ? rflagp[0] : (RES_F32_S ? 1 : 0);
    const int out_f32 = oflagp ? oflagp[0] : (OUT_F32_S ? 1 : 0);

    // epilogue: C/D layout col=lane&15, row=(lane>>4)*4+reg (m89/m91-verified)
    const int rq4 = (lane >> 4) * 4;
    const int coln = lane & 15;
#pragma unroll
    for (int mi = 0; mi < 4; ++mi) {
#pragma unroll
        for (int ni = 0; ni < 4; ++ni) {
            long col = n0 + waveN * 64 + ni * 16 + coln;
            float bv = (EPI >= 1) ? b2f(bias[col]) : 0.f;
#pragma unroll
            for (int r = 0; r < 4; ++r) {
                long row = m0 + waveM * 64 + mi * 16 + rq4 + r;
                if (row >= M) continue;
                long off = row * (long)N + col;
                float v = acc[mi][ni][r] + bv;
                if (EPI == 2) v += rd2(Rf, Rb, off, res_f32);
                if (out_f32) Cf[off] = v;
                else Cb[off] = f2b(v);
            }
        }
    }
}

// ---------------------------------------------------------------------------
// Window attention, MFMA version. One wave per (window, head). WS=7 -> 49
// tokens (padded to 64), hd=64. qkv: [Tc,1152] chunk-local token order,
// cols = s*384 + h*64 + d. out: [Tc,384] (window_reverse fused via scatter).
//
// S^T = mfma(K, Q): acc row = key = quad*4+reg (+16*mi), col = q = lane&15
// (+16*ni). Per-q softmax = 16 in-lane values + shfl_xor(16,32) across
// quads. P packed bf16 -> LDS [q][key] (reuses Q buffer); PV = mfma(P, VT):
// out row = q, col = d. LDS rows padded to 72 shorts (144B stride = 2-way
// banks, 16B-aligned for ds_read_b128). Pad keys >=49: s forced to -1e30
// (also kills NaN from uninit K rows); VT pad keys zeroed (0*NaN guard).
// ---------------------------------------------------------------------------
__global__ __launch_bounds__(64) void attn_kernel(
    const unsigned short* __restrict__ qkv,
    const unsigned short* __restrict__ rel_bias,
    unsigned short* __restrict__ out)
{
    __shared__ __align__(16) unsigned short k_lds[64 * 72];   // K: [key][d]
    __shared__ __align__(16) unsigned short v_lds[64 * 72];   // VT: [d][key]
    __shared__ __align__(16) unsigned short q_lds[64 * 72];   // Q: [q][d], then P: [q][key]

    const int w = blockIdx.x, hh = blockIdx.y;
    const int lane = threadIdx.x;
    const int b = w >> 6, wh = (w >> 3) & 7, ww = w & 7;
    const long base = (long)b * 3136;
    const unsigned short* src = qkv + hh * 64;

    // --- stage Q, K row-major [t][d] via 8B quads: 784 items, 13 iters ---
#pragma unroll
    for (int it = 0; it < 13; ++it) {
        int idx = it * 64 + lane;
        if (idx < 784) {
            int t = idx >> 4, d4 = (idx & 15) << 2;
            int pi = t / 7, pj = t % 7;
            const unsigned short* gp =
                src + (base + (wh * 7 + pi) * 56 + (ww * 7 + pj)) * 1152 + d4;
            *(ushort4*)(q_lds + t * 72 + d4) = *(const ushort4*)(gp);
            *(ushort4*)(k_lds + t * 72 + d4) = *(const ushort4*)(gp + 384);
        }
    }
    // --- stage V transposed: lane = d, loop keys (coalesced global) ---
    for (int p = 0; p < 49; ++p) {
        int pi = p / 7, pj = p % 7;
        v_lds[lane * 72 + p] =
            src[(base + (wh * 7 + pi) * 56 + (ww * 7 + pj)) * 1152 + 768 + lane];
    }
#pragma unroll
    for (int p = 49; p < 64; ++p) v_lds[lane * 72 + p] = 0;  // pad (0*NaN guard)
    __syncthreads();

    const int rq = lane & 15, quad = lane >> 4;

    // --- QK^T (swapped): S^T[key][q], 32 MFMAs ---
    bf16x8 kf[4][2], qf[4][2];
#pragma unroll
    for (int t4 = 0; t4 < 4; ++t4)
#pragma unroll
        for (int ks = 0; ks < 2; ++ks) {
            kf[t4][ks] = *(const bf16x8*)(k_lds + (t4 * 16 + rq) * 72 + ks * 32 + quad * 8);
            qf[t4][ks] = *(const bf16x8*)(q_lds + (t4 * 16 + rq) * 72 + ks * 32 + quad * 8);
        }
    f32x4 sa[4][4] = {};   // [key-tile mi][q-tile ni]
#pragma unroll
    for (int ks = 0; ks < 2; ++ks)
#pragma unroll
        for (int mi = 0; mi < 4; ++mi)
#pragma unroll
            for (int ni = 0; ni < 4; ++ni)
                sa[mi][ni] = __builtin_amdgcn_mfma_f32_16x16x32_bf16(
                    kf[mi][ks], qf[ni][ks], sa[mi][ni], 0, 0, 0);

    // --- softmax per q-column + P -> LDS (reuse q_lds; Q already in regs) ---
    const int kq = quad * 4;
#pragma unroll
    for (int ni = 0; ni < 4; ++ni) {
        int q = ni * 16 + rq;
        int qc = (q < 49) ? q : 48;        // clamp for in-bounds bias loads
        int yi = qc / 7, xi = qc % 7;
        float mx = -1e30f;
#pragma unroll
        for (int mi = 0; mi < 4; ++mi)
#pragma unroll
            for (int r = 0; r < 4; ++r) {
                int key = mi * 16 + kq + r;
                float s;
                if (key < 49) {
                    int yj = key / 7, xj = key % 7;
                    int idx = (yi - yj + 6) * 13 + (xi - xj + 6);
                    s = 0.125f * sa[mi][ni][r] + b2f(rel_bias[idx * 6 + hh]);
                } else s = -1e30f;         // pad mask (overwrites any NaN)
                sa[mi][ni][r] = s;
                mx = fmaxf(mx, s);
            }
        mx = fmaxf(mx, __shfl_xor(mx, 16));
        mx = fmaxf(mx, __shfl_xor(mx, 32));
        float sum = 0.f;
#pragma unroll
        for (int mi = 0; mi < 4; ++mi)
#pragma unroll
            for (int r = 0; r < 4; ++r) {
                float e = __expf(sa[mi][ni][r] - mx);
                sa[mi][ni][r] = e;
                sum += e;
            }
        sum += __shfl_xor(sum, 16);
        sum += __shfl_xor(sum, 32);
        float rinv = 1.f / sum;
#pragma unroll
        for (int mi = 0; mi < 4; ++mi) {
            unsigned int w0 = (unsigned int)f2b(sa[mi][ni][0] * rinv) |
                              ((unsigned int)f2b(sa[mi][ni][1] * rinv) << 16);
            unsigned int w1 = (unsigned int)f2b(sa[mi][ni][2] * rinv) |
                              ((unsigned int)f2b(sa[mi][ni][3] * rinv) << 16);
            *(unsigned int*)(q_lds + q * 72 + mi * 16 + kq)     = w0;
            *(unsigned int*)(q_lds + q * 72 + mi * 16 + kq + 2) = w1;
        }
    }
    __syncthreads();

    // --- PV: out[q][d] = P[q][key] * VT[d][key]^T, 32 MFMAs ---
    f32x4 oa[4][4] = {};   // [q-tile qt][d-tile dt]
#pragma unroll
    for (int ks = 0; ks < 2; ++ks) {
        bf16x8 pf[4], vf[4];
#pragma unroll
        for (int qt = 0; qt < 4; ++qt)
            pf[qt] = *(const bf16x8*)(q_lds + (qt * 16 + rq) * 72 + ks * 32 + quad * 8);
#pragma unroll
        for (int dt = 0; dt < 4; ++dt)
            vf[dt] = *(const bf16x8*)(v_lds + (dt * 16 + rq) * 72 + ks * 32 + quad * 8);
#pragma unroll
        for (int qt = 0; qt < 4; ++qt)
#pragma unroll
            for (int dt = 0; dt < 4; ++dt)
                oa[qt][dt] = __builtin_amdgcn_mfma_f32_16x16x32_bf16(
                    pf[qt], vf[dt], oa[qt][dt], 0, 0, 0);
    }

    // --- epilogue: scatter with fused window_reverse ---
#pragma unroll
    for (int qt = 0; qt < 4; ++qt)
#pragma unroll
        for (int r = 0; r < 4; ++r) {
            int q = qt * 16 + quad * 4 + r;
            if (q >= 49) continue;
            int yi = q / 7, xi = q % 7;
            long t = base + (long)(wh * 7 + yi) * 56 + (ww * 7 + xi);
            unsigned short* op = out + t * 384 + hh * 64;
#pragma unroll
            for (int dt = 0; dt < 4; ++dt)
                op[dt * 16 + rq] = f2b(oa[qt][dt][r]);
        }
}

// ---------------------------------------------------------------------------
// Depthwise 3x3 conv (SAME, zero-pad) + exact GELU. Channel-last [Tc,1536].
// Round-5: 8 ch/thread (u16x8 = 16B loads), k-major weights w_dwT[k][1536]
// so every load is coalesced 1KiB/wave. Block 192 (= 1536/8), grid = Tc.
// ---------------------------------------------------------------------------
__global__ __launch_bounds__(192) void dwconv_gelu(
    const unsigned short* __restrict__ h,
    const unsigned short* __restrict__ w_dwT,   // [9][1536]
    const unsigned short* __restrict__ b_dw,
    unsigned short* __restrict__ g)
{
    const long t = blockIdx.x;
    const int bb = (int)(t / 3136), n = (int)(t % 3136);
    const int r = n / 56, c = n % 56;
    const int ch = threadIdx.x * 8;

    float a[8];
    u16x8 bv = *(const u16x8*)(b_dw + ch);
#pragma unroll
    for (int i = 0; i < 8; ++i) a[i] = b2f(bv[i]);

#pragma unroll
    for (int dr = -1; dr <= 1; ++dr) {
        int rr = r + dr;
        if (rr < 0 || rr >= 56) continue;
#pragma unroll
        for (int dc = -1; dc <= 1; ++dc) {
            int cc = c + dc;
            if (cc < 0 || cc >= 56) continue;
            int k = (dr + 1) * 3 + (dc + 1);
            long off = ((long)bb * 3136 + rr * 56 + cc) * 1536 + ch;
            u16x8 hv = *(const u16x8*)(h + off);
            u16x8 wv = *(const u16x8*)(w_dwT + k * 1536 + ch);
#pragma unroll
            for (int i = 0; i < 8; ++i) a[i] += b2f(hv[i]) * b2f(wv[i]);
        }
    }
    u16x8 ov;
#pragma unroll
    for (int i = 0; i < 8; ++i) {
        float v = 0.5f * a[i] * (1.f + erff(a[i] * 0.70710678118654752f));
        ov[i] = f2b(v);
    }
    *(u16x8*)(g + t * 1536 + ch) = ov;
}

// ---------------------------------------------------------------------------
extern "C" void kernel_launch(void* const* d_in, const int* in_sizes, int n_in,
                              void* d_out, int out_size, void* d_ws, size_t ws_size,
                              hipStream_t stream)
{
    const void* x      = d_in[0];
    const void* gamma1 = d_in[1];
    const void* beta1  = d_in[2];
    const void* w_qkv  = d_in[3];
    const void* w_proj = d_in[4];
    const void* b_proj = d_in[5];
    const void* relb   = d_in[6];
    const void* gamma2 = d_in[7];
    const void* beta2  = d_in[8];
    const void* w_fc1  = d_in[9];
    const void* b_fc1  = d_in[10];
    const void* w_dw   = d_in[11];
    const void* b_dw   = d_in[12];
    const void* w_fc2  = d_in[13];
    const void* b_fc2  = d_in[14];

    const int NIMG = 32, NPI = 3136;          // images, tokens/image

    // --- ws layout: flag | smalls(bf16) | transposed weights(bf16) | chunk ---
    int* flag = (int*)d_ws;                                        // 16 B slot
    unsigned short* smalls = (unsigned short*)((char*)d_ws + 16);  // 20214 el
    unsigned short* wqkvT  = (unsigned short*)((char*)d_ws + 16 + 20224 * 2);
    unsigned short* wprojT = wqkvT + 1152 * 384;
    unsigned short* wfc1T  = wprojT + 384 * 384;
    unsigned short* wfc2T  = wfc1T + 1536 * 384;
    const size_t WB = 16 + 20224 * 2 +
        ((size_t)1152 * 384 + 384 * 384 + 1536 * 384 + 384 * 1536) * 2;
    char* chunk_base = (char*)d_ws + WB;

    const unsigned short* c_g1   = smalls;
    const unsigned short* c_b1   = smalls + 384;
    const unsigned short* c_bp   = smalls + 768;
    const unsigned short* c_g2   = smalls + 1152;
    const unsigned short* c_b2   = smalls + 1536;
    const unsigned short* c_bf1  = smalls + 1920;
    const unsigned short* c_wdwT = smalls + 3456;   // k-major [9][1536]
    const unsigned short* c_bdw  = smalls + 17280;
    const unsigned short* c_bf2  = smalls + 18816;
    const unsigned short* c_rb   = smalls + 19200;

    // per-image chunk bytes: x1 fp32 + r1 bf16 + r2 bf16 = 24,084,480 B
    const size_t PER_IMG = (size_t)NPI * 384 * 4 + 2 * (size_t)NPI * 1536 * 2;
    int ipc = NIMG;   // ws_size launch-invariant -> same schedule every call
    while (ipc > 1 && WB + PER_IMG * (size_t)ipc > ws_size) ipc >>= 1;

    detect_dtype<<<1, 64, 0, stream>>>((const unsigned int*)gamma1, flag);
    convert_smalls<<<80, 256, 0, stream>>>(flag, gamma1, beta1, b_proj, gamma2,
        beta2, b_fc1, w_dw, b_dw, b_fc2, relb, smalls);
    transpose_any<<<dim3(36, 12), 256, 0, stream>>>(w_qkv, wqkvT, 384, 1152, flag);
    transpose_any<<<dim3(12, 12), 256, 0, stream>>>(w_proj, wprojT, 384, 384, flag);
    transpose_any<<<dim3(48, 12), 256, 0, stream>>>(w_fc1, wfc1T, 384, 1536, flag);
    transpose_any<<<dim3(12, 48), 256, 0, stream>>>(w_fc2, wfc2T, 1536, 384, flag);

    for (int i0 = 0; i0 < NIMG; i0 += ipc) {
        const int Tc = ipc * NPI;
        const long tb = (long)i0 * NPI;
        const int GM = (Tc + 255) / 256;

        float* x1 = (float*)chunk_base;
        unsigned short* r1 = (unsigned short*)(chunk_base + (size_t)Tc * 384 * 4);
        unsigned short* r2 = r1 + (size_t)Tc * 1536;

        unsigned short* xn      = r1;                       // LN1 out
        unsigned short* hbuf    = r1;                       // fc1 out
        unsigned short* qkv     = r2;
        unsigned short* attnout = r2 + (size_t)Tc * 1152;
        unsigned short* ybuf    = r2;                       // LN2 out
        unsigned short* gbuf    = r2;                       // gelu out

        // dual views of input slice / output slice (same element index)
        const float* xf = (const float*)x + tb * 384;
        const unsigned short* xb = (const unsigned short*)x + tb * 384;
        float* of = (float*)d_out + tb * 384;
        unsigned short* ob = (unsigned short*)d_out + tb * 384;

        // attention branch
        ln_kernel<<<Tc / 4, 256, 0, stream>>>(xf, xb, c_g1, c_b1, xn, Tc, flag, 0);
        gemm_nt<0, false, false><<<GM * 9, 512, 0, stream>>>(
            xn, wqkvT, nullptr, qkv, nullptr, nullptr, nullptr,
            Tc, 1152, 384, nullptr, nullptr);
        attn_kernel<<<dim3(ipc * 64, 6), 64, 0, stream>>>(qkv, c_rb, attnout);
        gemm_nt<2, true, false><<<GM * 3, 512, 0, stream>>>(
            attnout, wprojT, x1, nullptr, c_bp, xf, xb,
            Tc, 384, 384, flag, nullptr);

        // ConvFFN branch
        ln_kernel<<<Tc / 4, 256, 0, stream>>>(x1, nullptr, c_g2, c_b2, ybuf, Tc,
                                              flag, 1);
        gemm_nt<1, false, false><<<GM * 12, 512, 0, stream>>>(
            ybuf, wfc1T, nullptr, hbuf, c_bf1, nullptr, nullptr,
            Tc, 1536, 384, nullptr, nullptr);
        dwconv_gelu<<<Tc, 192, 0, stream>>>(hbuf, c_wdwT, c_bdw, gbuf);
        gemm_nt<2, false, true><<<GM * 3, 512, 0, stream>>>(
            gbuf, wfc2T, of, ob, c_bf2, x1, nullptr,
            Tc, 384, 1536, nullptr, flag);
    }
}

// Round 6
// 1916.732 us; speedup vs baseline: 1.1154x; 1.1154x over previous
//
#include <hip/hip_runtime.h>
#include <math.h>

// ---------------------------------------------------------------------------
// TinyViT block on MI355X (gfx950). Internal compute bf16 MFMA + fp32 accum.
// Round-11: gemm_nt staging switched from global_load_lds DMA to REG-STAGED
// (T14): global_load_dwordx4 -> VGPR -> ds_write_b128, double-buffered.
// Evidence: rounds 6/7/8/10 (four schedules: 2-drain, dbuf, counted depth-2,
// 4-phase depth-3+setprio) ALL cost ~5.2e-3 cy/MAC (~236 TF) with MFMA 9%,
// VALU 7%, HBM 10%, conflicts 0, occupancy 17-26% -> work-proportional,
// schedule-invariant, no saturated resource. The one shared mechanism is the
// global_load_lds DMA transport; its completion path is invisible to SQ/TCC
// counters and Little's law shows ~1KB in flight/CU despite 18 queued loads.
// This round swaps ONLY the transport; fragment math, epilogue, XOR chunk
// layout (0 conflicts, r10-verified) and XCD remap (FETCH 264->137MB) stay.
// Loop: {sync; LOADG(t+1)->regs; compute(t); sync; WRITE(t+1)->lds[cur^1]}.
// Compiler issues loads before MFMAs (no dep) and inserts counted vmcnt
// before the ds_writes -> HBM latency hides under the 32-MFMA phase.
// attn (round-6 MFMA), dwconv (round-5), LN, transposes unchanged.
// ---------------------------------------------------------------------------

typedef __bf16 bf16x8 __attribute__((ext_vector_type(8)));
typedef float f32x4 __attribute__((ext_vector_type(4)));
typedef unsigned short u16x8 __attribute__((ext_vector_type(8)));

__device__ __forceinline__ float b2f(unsigned short u) {
    union { unsigned int i; float f; } x;
    x.i = ((unsigned int)u) << 16;
    return x.f;
}
__device__ __forceinline__ unsigned short f2b(float f) {
    union { float f; unsigned int i; } x;
    x.f = f;
    unsigned int i = x.i;
    return (unsigned short)((i + 0x7fffu + ((i >> 16) & 1u)) >> 16);
}
// element i of a dual-view buffer (fp32 view pf, bf16 view pb), per flag
__device__ __forceinline__ float rd2(const float* pf, const unsigned short* pb,
                                     long i, int f32) {
    return f32 ? pf[i] : b2f(pb[i]);
}

// ---------------------------------------------------------------------------
__global__ void detect_dtype(const unsigned int* __restrict__ gamma1,
                             int* __restrict__ flag)
{
    if (threadIdx.x == 0) flag[0] = (gamma1[0] == 0x3F800000u) ? 1 : 0;
}

// ---------------------------------------------------------------------------
// Convert all small params to one canonical bf16 buffer.
// layout (elems): g1 0 | b1 384 | bp 768 | g2 1152 | b2 1536 | bf1 1920
//                 | wdwT 3456 (k-major: [k][1536]) | bdw 17280 | bf2 18816
//                 | rb 19200 | end 20214
// ---------------------------------------------------------------------------
__global__ __launch_bounds__(256) void convert_smalls(
    const int* __restrict__ flag,
    const void* g1, const void* b1, const void* bp, const void* g2,
    const void* b2, const void* bf1, const void* wdw, const void* bdw,
    const void* bf2, const void* rb, unsigned short* __restrict__ dst)
{
    int i = blockIdx.x * 256 + threadIdx.x;
    if (i >= 20214) return;
    const int f = flag[0];
    const void* src; long j; int o = i;
    if      (i < 384)   { src = g1;  j = i; }
    else if (i < 768)   { src = b1;  j = i - 384; }
    else if (i < 1152)  { src = bp;  j = i - 768; }
    else if (i < 1536)  { src = g2;  j = i - 1152; }
    else if (i < 1920)  { src = b2;  j = i - 1536; }
    else if (i < 3456)  { src = bf1; j = i - 1920; }
    else if (i < 17280) {
        // destination index i-3456 = k*1536 + ch (k-major); source = ch*9 + k
        int d = i - 3456, k = d / 1536, ch = d % 1536;
        src = wdw; j = (long)ch * 9 + k;
    }
    else if (i < 18816) { src = bdw; j = i - 17280; }
    else if (i < 19200) { src = bf2; j = i - 18816; }
    else                { src = rb;  j = i - 19200; }
    float v = f ? ((const float*)src)[j] : b2f(((const unsigned short*)src)[j]);
    dst[o] = f2b(v);
}

// ---------------------------------------------------------------------------
// Flag-aware tiled transpose to bf16: out[c*R + r] = (bf16)in[r*C + c]
// ---------------------------------------------------------------------------
__global__ __launch_bounds__(256) void transpose_any(
    const void* __restrict__ in, unsigned short* __restrict__ out,
    int R, int C, const int* __restrict__ flag)
{
    __shared__ unsigned short tile[32][33];
    const int f = flag[0];
    int tx = threadIdx.x & 31, ty = threadIdx.x >> 5;
    int rb = blockIdx.y * 32, cb = blockIdx.x * 32;
#pragma unroll
    for (int i = 0; i < 32; i += 8) {
        int r = rb + ty + i, c = cb + tx;
        if (r < R && c < C)
            tile[ty + i][tx] = f2b(rd2((const float*)in,
                                       (const unsigned short*)in,
                                       (long)r * C + c, f));
    }
    __syncthreads();
#pragma unroll
    for (int i = 0; i < 32; i += 8) {
        int c = cb + ty + i, r = rb + tx;
        if (c < C && r < R) out[(long)c * R + r] = tile[tx][ty + i];
    }
}

// ---------------------------------------------------------------------------
// LayerNorm over C=384, one wave per token. Input = dual view (xf/xb) per
// flag; force_f32=1 -> always fp32 (flagp ignored). gamma/beta bf16.
// ---------------------------------------------------------------------------
__global__ __launch_bounds__(256) void ln_kernel(
    const float* __restrict__ xf, const unsigned short* __restrict__ xb,
    const unsigned short* __restrict__ gamma,
    const unsigned short* __restrict__ beta,
    unsigned short* __restrict__ yout, int T,
    const int* __restrict__ flagp, int force_f32)
{
    int w = blockIdx.x * 4 + (threadIdx.x >> 6);
    int lane = threadIdx.x & 63;
    if (w >= T) return;
    const int f32 = force_f32 ? 1 : flagp[0];
    long base = (long)w * 384;
    float v[6];
    float s = 0.f;
#pragma unroll
    for (int i = 0; i < 6; ++i) {
        v[i] = rd2(xf, xb, base + lane + i * 64, f32);
        s += v[i];
    }
#pragma unroll
    for (int o = 32; o > 0; o >>= 1) s += __shfl_xor(s, o);
    float mu = s * (1.f / 384.f);
    float q = 0.f;
#pragma unroll
    for (int i = 0; i < 6; ++i) { float d = v[i] - mu; q += d * d; }
#pragma unroll
    for (int o = 32; o > 0; o >>= 1) q += __shfl_xor(q, o);
    float rs = rsqrtf(q * (1.f / 384.f) + 1e-5f);
#pragma unroll
    for (int i = 0; i < 6; ++i) {
        int cc = lane + i * 64;
        yout[base + cc] = f2b((v[i] - mu) * rs * b2f(gamma[cc]) + b2f(beta[cc]));
    }
}

// ---------------------------------------------------------------------------
// GEMM: C[M,N] = A[M,K] * BT[N,K]^T, bf16 in, fp32 accum.
// EPI: 0=store, 1=+bias, 2=+bias+residual. Residual & output are dual-view
// (fp32 ptr + bf16 ptr); runtime flags may override the static dtype bools.
// N%128==0, K%64==0; M arbitrary (A-row clamp + store guard).
//
// Round-11: BM=BN=128, BK=64, 256 thr = 4 waves (2x2), wave = 64x64 via
// 4x4 16x16x32 tiles (fragment + C/D math identical to verified versions).
// REG-STAGED double-buffer (T14): per K-tile each thread owns 4 A-chunks and
// 4 B-chunks (16B each); LDS chunk map row r, k-quad q -> slot q^(r&7)
// (chunk idx r*8 + (q^(r&7)), 0 conflicts, r10-verified). Loop:
//   sync#1 (buf[cur] writes visible)
//   LOADG(t+1): 8x global_load_dwordx4 -> regs  (flies during compute)
//   compute buf[cur]: 16 ds_read_b128 + 32 MFMA
//   sync#2 (all waves done reading buf[cur^1])
//   WRITE(t+1): 8x ds_write_b128 -> buf[cur^1]  (compiler waits vmcnt here)
// LDS 64KB -> 2 blocks/CU. 1-D grid + bijective XCD-chunked remap (m204).
// ---------------------------------------------------------------------------
template<int EPI, bool OUT_F32_S, bool RES_F32_S>
__global__ __launch_bounds__(256) void gemm_nt(
    const unsigned short* __restrict__ A,
    const unsigned short* __restrict__ BT,
    float* __restrict__ Cf, unsigned short* __restrict__ Cb,
    const unsigned short* __restrict__ bias,
    const float* __restrict__ Rf, const unsigned short* __restrict__ Rb,
    int M, int N, int K,
    const int* __restrict__ rflagp, const int* __restrict__ oflagp)
{
    __shared__ __align__(16) unsigned short ldsA[2][128 * 64];   // 32 KB
    __shared__ __align__(16) unsigned short ldsB[2][128 * 64];   // 32 KB
    const int tid = threadIdx.x;               // 0..255
    const int lane = tid & 63;
    const int wv = tid >> 6;                   // 0..3
    const int waveM = wv >> 1, waveN = wv & 1; // 2 x 2 wave grid

    // ---- bijective XCD-chunked remap (m204), n-fast logical order ----
    const int nwg = (int)gridDim.x;
    const int orig = (int)blockIdx.x;
    const int qq = nwg >> 3, rr = nwg & 7, xcd = orig & 7;
    const int wgid = (xcd < rr ? xcd * (qq + 1)
                               : rr * (qq + 1) + (xcd - rr) * qq) + (orig >> 3);
    const int NB = N >> 7;                     // N/128 blocks in n
    const long m0 = (long)(wgid / NB) * 128;
    const long n0 = (long)(wgid % NB) * 128;

    f32x4 acc[4][4] = {};

    // ---- staging ownership: A,B each 1024 16B-chunks (4/thread).
    // chunk c: row=c>>3, slot=c&7, global k-quad = slot^(row&7).
    const unsigned short* aptr[4];
    const unsigned short* bptr[4];
#pragma unroll
    for (int i = 0; i < 4; ++i) {
        int c = tid + i * 256, r = c >> 3, q = (c & 7) ^ (r & 7);
        long row = m0 + r; if (row >= M) row = M - 1;   // clamp (dup ok)
        aptr[i] = A + row * (long)K + q * 8;
        bptr[i] = BT + (n0 + r) * (long)K + q * 8;
    }

    u16x8 sa0, sa1, sa2, sa3, sb0, sb1, sb2, sb3;   // staged tile (regs)

    auto LOADG = [&](int kt) {
        sa0 = *(const u16x8*)(aptr[0] + kt);
        sa1 = *(const u16x8*)(aptr[1] + kt);
        sa2 = *(const u16x8*)(aptr[2] + kt);
        sa3 = *(const u16x8*)(aptr[3] + kt);
        sb0 = *(const u16x8*)(bptr[0] + kt);
        sb1 = *(const u16x8*)(bptr[1] + kt);
        sb2 = *(const u16x8*)(bptr[2] + kt);
        sb3 = *(const u16x8*)(bptr[3] + kt);
    };
    auto WRITE = [&](int buf) {
        *(u16x8*)(&ldsA[buf][(tid          ) * 8]) = sa0;
        *(u16x8*)(&ldsA[buf][(tid + 1 * 256) * 8]) = sa1;
        *(u16x8*)(&ldsA[buf][(tid + 2 * 256) * 8]) = sa2;
        *(u16x8*)(&ldsA[buf][(tid + 3 * 256) * 8]) = sa3;
        *(u16x8*)(&ldsB[buf][(tid          ) * 8]) = sb0;
        *(u16x8*)(&ldsB[buf][(tid + 1 * 256) * 8]) = sb1;
        *(u16x8*)(&ldsB[buf][(tid + 2 * 256) * 8]) = sb2;
        *(u16x8*)(&ldsB[buf][(tid + 3 * 256) * 8]) = sb3;
    };

    const int nt = K >> 6;                     // K/64 (384->6, 1536->24)
    const int rq = lane & 15, quad = lane >> 4;

    // prologue: tile 0 through regs into buf 0
    LOADG(0);
    WRITE(0);

    int cur = 0;
    for (int t = 0; t < nt; ++t) {
        __syncthreads();                       // buf[cur] writes visible
        if (t + 1 < nt) LOADG((t + 1) * 64);   // prefetch next tile -> regs

        const unsigned short* As = ldsA[cur];
        const unsigned short* Bs = ldsB[cur];
#pragma unroll
        for (int h = 0; h < 2; ++h) {
            bf16x8 av[4], bv[4];
#pragma unroll
            for (int mi = 0; mi < 4; ++mi) {
                int R = waveM * 64 + mi * 16 + rq;
                av[mi] = *(const bf16x8*)(As + (R * 8 + ((h * 4 + quad) ^ (R & 7))) * 8);
            }
#pragma unroll
            for (int ni = 0; ni < 4; ++ni) {
                int R = waveN * 64 + ni * 16 + rq;
                bv[ni] = *(const bf16x8*)(Bs + (R * 8 + ((h * 4 + quad) ^ (R & 7))) * 8);
            }
#pragma unroll
            for (int mi = 0; mi < 4; ++mi)
#pragma unroll
                for (int ni = 0; ni < 4; ++ni)
                    acc[mi][ni] = __builtin_amdgcn_mfma_f32_16x16x32_bf16(
                        av[mi], bv[ni], acc[mi][ni], 0, 0, 0);
        }

        __syncthreads();                       // all reads of buf[cur^1] done
        if (t + 1 < nt) WRITE(cur ^ 1);        // land prefetch (vmcnt here)
        cur ^= 1;
    }

    const int res_f32 = rflagp ? rflagp[0] : (RES_F32_S ? 1 : 0);
    const int out_f32 = oflagp ? oflagp[0] : (OUT_F32_S ? 1 : 0);

    // epilogue: C/D layout col=lane&15, row=(lane>>4)*4+reg (m89/m91-verified)
    const int rq4 = (lane >> 4) * 4;
    const int coln = lane & 15;
#pragma unroll
    for (int mi = 0; mi < 4; ++mi) {
#pragma unroll
        for (int ni = 0; ni < 4; ++ni) {
            long col = n0 + waveN * 64 + ni * 16 + coln;
            float bv = (EPI >= 1) ? b2f(bias[col]) : 0.f;
#pragma unroll
            for (int r = 0; r < 4; ++r) {
                long row = m0 + waveM * 64 + mi * 16 + rq4 + r;
                if (row >= M) continue;
                long off = row * (long)N + col;
                float v = acc[mi][ni][r] + bv;
                if (EPI == 2) v += rd2(Rf, Rb, off, res_f32);
                if (out_f32) Cf[off] = v;
                else Cb[off] = f2b(v);
            }
        }
    }
}

// ---------------------------------------------------------------------------
// Window attention, MFMA version. One wave per (window, head). WS=7 -> 49
// tokens (padded to 64), hd=64. qkv: [Tc,1152] chunk-local token order,
// cols = s*384 + h*64 + d. out: [Tc,384] (window_reverse fused via scatter).
//
// S^T = mfma(K, Q): acc row = key = quad*4+reg (+16*mi), col = q = lane&15
// (+16*ni). Per-q softmax = 16 in-lane values + shfl_xor(16,32) across
// quads. P packed bf16 -> LDS [q][key] (reuses Q buffer); PV = mfma(P, VT):
// out row = q, col = d. LDS rows padded to 72 shorts (144B stride = 2-way
// banks, 16B-aligned for ds_read_b128). Pad keys >=49: s forced to -1e30
// (also kills NaN from uninit K rows); VT pad keys zeroed (0*NaN guard).
// ---------------------------------------------------------------------------
__global__ __launch_bounds__(64) void attn_kernel(
    const unsigned short* __restrict__ qkv,
    const unsigned short* __restrict__ rel_bias,
    unsigned short* __restrict__ out)
{
    __shared__ __align__(16) unsigned short k_lds[64 * 72];   // K: [key][d]
    __shared__ __align__(16) unsigned short v_lds[64 * 72];   // VT: [d][key]
    __shared__ __align__(16) unsigned short q_lds[64 * 72];   // Q: [q][d], then P: [q][key]

    const int w = blockIdx.x, hh = blockIdx.y;
    const int lane = threadIdx.x;
    const int b = w >> 6, wh = (w >> 3) & 7, ww = w & 7;
    const long base = (long)b * 3136;
    const unsigned short* src = qkv + hh * 64;

    // --- stage Q, K row-major [t][d] via 8B quads: 784 items, 13 iters ---
#pragma unroll
    for (int it = 0; it < 13; ++it) {
        int idx = it * 64 + lane;
        if (idx < 784) {
            int t = idx >> 4, d4 = (idx & 15) << 2;
            int pi = t / 7, pj = t % 7;
            const unsigned short* gp =
                src + (base + (wh * 7 + pi) * 56 + (ww * 7 + pj)) * 1152 + d4;
            *(ushort4*)(q_lds + t * 72 + d4) = *(const ushort4*)(gp);
            *(ushort4*)(k_lds + t * 72 + d4) = *(const ushort4*)(gp + 384);
        }
    }
    // --- stage V transposed: lane = d, loop keys (coalesced global) ---
    for (int p = 0; p < 49; ++p) {
        int pi = p / 7, pj = p % 7;
        v_lds[lane * 72 + p] =
            src[(base + (wh * 7 + pi) * 56 + (ww * 7 + pj)) * 1152 + 768 + lane];
    }
#pragma unroll
    for (int p = 49; p < 64; ++p) v_lds[lane * 72 + p] = 0;  // pad (0*NaN guard)
    __syncthreads();

    const int rq = lane & 15, quad = lane >> 4;

    // --- QK^T (swapped): S^T[key][q], 32 MFMAs ---
    bf16x8 kf[4][2], qf[4][2];
#pragma unroll
    for (int t4 = 0; t4 < 4; ++t4)
#pragma unroll
        for (int ks = 0; ks < 2; ++ks) {
            kf[t4][ks] = *(const bf16x8*)(k_lds + (t4 * 16 + rq) * 72 + ks * 32 + quad * 8);
            qf[t4][ks] = *(const bf16x8*)(q_lds + (t4 * 16 + rq) * 72 + ks * 32 + quad * 8);
        }
    f32x4 sa[4][4] = {};   // [key-tile mi][q-tile ni]
#pragma unroll
    for (int ks = 0; ks < 2; ++ks)
#pragma unroll
        for (int mi = 0; mi < 4; ++mi)
#pragma unroll
            for (int ni = 0; ni < 4; ++ni)
                sa[mi][ni] = __builtin_amdgcn_mfma_f32_16x16x32_bf16(
                    kf[mi][ks], qf[ni][ks], sa[mi][ni], 0, 0, 0);

    // --- softmax per q-column + P -> LDS (reuse q_lds; Q already in regs) ---
    const int kq = quad * 4;
#pragma unroll
    for (int ni = 0; ni < 4; ++ni) {
        int q = ni * 16 + rq;
        int qc = (q < 49) ? q : 48;        // clamp for in-bounds bias loads
        int yi = qc / 7, xi = qc % 7;
        float mx = -1e30f;
#pragma unroll
        for (int mi = 0; mi < 4; ++mi)
#pragma unroll
            for (int r = 0; r < 4; ++r) {
                int key = mi * 16 + kq + r;
                float s;
                if (key < 49) {
                    int yj = key / 7, xj = key % 7;
                    int idx = (yi - yj + 6) * 13 + (xi - xj + 6);
                    s = 0.125f * sa[mi][ni][r] + b2f(rel_bias[idx * 6 + hh]);
                } else s = -1e30f;         // pad mask (overwrites any NaN)
                sa[mi][ni][r] = s;
                mx = fmaxf(mx, s);
            }
        mx = fmaxf(mx, __shfl_xor(mx, 16));
        mx = fmaxf(mx, __shfl_xor(mx, 32));
        float sum = 0.f;
#pragma unroll
        for (int mi = 0; mi < 4; ++mi)
#pragma unroll
            for (int r = 0; r < 4; ++r) {
                float e = __expf(sa[mi][ni][r] - mx);
                sa[mi][ni][r] = e;
                sum += e;
            }
        sum += __shfl_xor(sum, 16);
        sum += __shfl_xor(sum, 32);
        float rinv = 1.f / sum;
#pragma unroll
        for (int mi = 0; mi < 4; ++mi) {
            unsigned int w0 = (unsigned int)f2b(sa[mi][ni][0] * rinv) |
                              ((unsigned int)f2b(sa[mi][ni][1] * rinv) << 16);
            unsigned int w1 = (unsigned int)f2b(sa[mi][ni][2] * rinv) |
                              ((unsigned int)f2b(sa[mi][ni][3] * rinv) << 16);
            *(unsigned int*)(q_lds + q * 72 + mi * 16 + kq)     = w0;
            *(unsigned int*)(q_lds + q * 72 + mi * 16 + kq + 2) = w1;
        }
    }
    __syncthreads();

    // --- PV: out[q][d] = P[q][key] * VT[d][key]^T, 32 MFMAs ---
    f32x4 oa[4][4] = {};   // [q-tile qt][d-tile dt]
#pragma unroll
    for (int ks = 0; ks < 2; ++ks) {
        bf16x8 pf[4], vf[4];
#pragma unroll
        for (int qt = 0; qt < 4; ++qt)
            pf[qt] = *(const bf16x8*)(q_lds + (qt * 16 + rq) * 72 + ks * 32 + quad * 8);
#pragma unroll
        for (int dt = 0; dt < 4; ++dt)
            vf[dt] = *(const bf16x8*)(v_lds + (dt * 16 + rq) * 72 + ks * 32 + quad * 8);
#pragma unroll
        for (int qt = 0; qt < 4; ++qt)
#pragma unroll
            for (int dt = 0; dt < 4; ++dt)
                oa[qt][dt] = __builtin_amdgcn_mfma_f32_16x16x32_bf16(
                    pf[qt], vf[dt], oa[qt][dt], 0, 0, 0);
    }

    // --- epilogue: scatter with fused window_reverse ---
#pragma unroll
    for (int qt = 0; qt < 4; ++qt)
#pragma unroll
        for (int r = 0; r < 4; ++r) {
            int q = qt * 16 + quad * 4 + r;
            if (q >= 49) continue;
            int yi = q / 7, xi = q % 7;
            long t = base + (long)(wh * 7 + yi) * 56 + (ww * 7 + xi);
            unsigned short* op = out + t * 384 + hh * 64;
#pragma unroll
            for (int dt = 0; dt < 4; ++dt)
                op[dt * 16 + rq] = f2b(oa[qt][dt][r]);
        }
}

// ---------------------------------------------------------------------------
// Depthwise 3x3 conv (SAME, zero-pad) + exact GELU. Channel-last [Tc,1536].
// Round-5: 8 ch/thread (u16x8 = 16B loads), k-major weights w_dwT[k][1536]
// so every load is coalesced 1KiB/wave. Block 192 (= 1536/8), grid = Tc.
// ---------------------------------------------------------------------------
__global__ __launch_bounds__(192) void dwconv_gelu(
    const unsigned short* __restrict__ h,
    const unsigned short* __restrict__ w_dwT,   // [9][1536]
    const unsigned short* __restrict__ b_dw,
    unsigned short* __restrict__ g)
{
    const long t = blockIdx.x;
    const int bb = (int)(t / 3136), n = (int)(t % 3136);
    const int r = n / 56, c = n % 56;
    const int ch = threadIdx.x * 8;

    float a[8];
    u16x8 bv = *(const u16x8*)(b_dw + ch);
#pragma unroll
    for (int i = 0; i < 8; ++i) a[i] = b2f(bv[i]);

#pragma unroll
    for (int dr = -1; dr <= 1; ++dr) {
        int rr = r + dr;
        if (rr < 0 || rr >= 56) continue;
#pragma unroll
        for (int dc = -1; dc <= 1; ++dc) {
            int cc = c + dc;
            if (cc < 0 || cc >= 56) continue;
            int k = (dr + 1) * 3 + (dc + 1);
            long off = ((long)bb * 3136 + rr * 56 + cc) * 1536 + ch;
            u16x8 hv = *(const u16x8*)(h + off);
            u16x8 wv = *(const u16x8*)(w_dwT + k * 1536 + ch);
#pragma unroll
            for (int i = 0; i < 8; ++i) a[i] += b2f(hv[i]) * b2f(wv[i]);
        }
    }
    u16x8 ov;
#pragma unroll
    for (int i = 0; i < 8; ++i) {
        float v = 0.5f * a[i] * (1.f + erff(a[i] * 0.70710678118654752f));
        ov[i] = f2b(v);
    }
    *(u16x8*)(g + t * 1536 + ch) = ov;
}

// ---------------------------------------------------------------------------
extern "C" void kernel_launch(void* const* d_in, const int* in_sizes, int n_in,
                              void* d_out, int out_size, void* d_ws, size_t ws_size,
                              hipStream_t stream)
{
    const void* x      = d_in[0];
    const void* gamma1 = d_in[1];
    const void* beta1  = d_in[2];
    const void* w_qkv  = d_in[3];
    const void* w_proj = d_in[4];
    const void* b_proj = d_in[5];
    const void* relb   = d_in[6];
    const void* gamma2 = d_in[7];
    const void* beta2  = d_in[8];
    const void* w_fc1  = d_in[9];
    const void* b_fc1  = d_in[10];
    const void* w_dw   = d_in[11];
    const void* b_dw   = d_in[12];
    const void* w_fc2  = d_in[13];
    const void* b_fc2  = d_in[14];

    const int NIMG = 32, NPI = 3136;          // images, tokens/image

    // --- ws layout: flag | smalls(bf16) | transposed weights(bf16) | chunk ---
    int* flag = (int*)d_ws;                                        // 16 B slot
    unsigned short* smalls = (unsigned short*)((char*)d_ws + 16);  // 20214 el
    unsigned short* wqkvT  = (unsigned short*)((char*)d_ws + 16 + 20224 * 2);
    unsigned short* wprojT = wqkvT + 1152 * 384;
    unsigned short* wfc1T  = wprojT + 384 * 384;
    unsigned short* wfc2T  = wfc1T + 1536 * 384;
    const size_t WB = 16 + 20224 * 2 +
        ((size_t)1152 * 384 + 384 * 384 + 1536 * 384 + 384 * 1536) * 2;
    char* chunk_base = (char*)d_ws + WB;

    const unsigned short* c_g1   = smalls;
    const unsigned short* c_b1   = smalls + 384;
    const unsigned short* c_bp   = smalls + 768;
    const unsigned short* c_g2   = smalls + 1152;
    const unsigned short* c_b2   = smalls + 1536;
    const unsigned short* c_bf1  = smalls + 1920;
    const unsigned short* c_wdwT = smalls + 3456;   // k-major [9][1536]
    const unsigned short* c_bdw  = smalls + 17280;
    const unsigned short* c_bf2  = smalls + 18816;
    const unsigned short* c_rb   = smalls + 19200;

    // per-image chunk bytes: x1 fp32 + r1 bf16 + r2 bf16 = 24,084,480 B
    const size_t PER_IMG = (size_t)NPI * 384 * 4 + 2 * (size_t)NPI * 1536 * 2;
    int ipc = NIMG;   // ws_size launch-invariant -> same schedule every call
    while (ipc > 1 && WB + PER_IMG * (size_t)ipc > ws_size) ipc >>= 1;

    detect_dtype<<<1, 64, 0, stream>>>((const unsigned int*)gamma1, flag);
    convert_smalls<<<80, 256, 0, stream>>>(flag, gamma1, beta1, b_proj, gamma2,
        beta2, b_fc1, w_dw, b_dw, b_fc2, relb, smalls);
    transpose_any<<<dim3(36, 12), 256, 0, stream>>>(w_qkv, wqkvT, 384, 1152, flag);
    transpose_any<<<dim3(12, 12), 256, 0, stream>>>(w_proj, wprojT, 384, 384, flag);
    transpose_any<<<dim3(48, 12), 256, 0, stream>>>(w_fc1, wfc1T, 384, 1536, flag);
    transpose_any<<<dim3(12, 48), 256, 0, stream>>>(w_fc2, wfc2T, 1536, 384, flag);

    for (int i0 = 0; i0 < NIMG; i0 += ipc) {
        const int Tc = ipc * NPI;
        const long tb = (long)i0 * NPI;
        const int GM = (Tc + 127) / 128;

        float* x1 = (float*)chunk_base;
        unsigned short* r1 = (unsigned short*)(chunk_base + (size_t)Tc * 384 * 4);
        unsigned short* r2 = r1 + (size_t)Tc * 1536;

        unsigned short* xn      = r1;                       // LN1 out
        unsigned short* hbuf    = r1;                       // fc1 out
        unsigned short* qkv     = r2;
        unsigned short* attnout = r2 + (size_t)Tc * 1152;
        unsigned short* ybuf    = r2;                       // LN2 out
        unsigned short* gbuf    = r2;                       // gelu out

        // dual views of input slice / output slice (same element index)
        const float* xf = (const float*)x + tb * 384;
        const unsigned short* xb = (const unsigned short*)x + tb * 384;
        float* of = (float*)d_out + tb * 384;
        unsigned short* ob = (unsigned short*)d_out + tb * 384;

        // attention branch
        ln_kernel<<<Tc / 4, 256, 0, stream>>>(xf, xb, c_g1, c_b1, xn, Tc, flag, 0);
        gemm_nt<0, false, false><<<GM * 9, 256, 0, stream>>>(
            xn, wqkvT, nullptr, qkv, nullptr, nullptr, nullptr,
            Tc, 1152, 384, nullptr, nullptr);
        attn_kernel<<<dim3(ipc * 64, 6), 64, 0, stream>>>(qkv, c_rb, attnout);
        gemm_nt<2, true, false><<<GM * 3, 256, 0, stream>>>(
            attnout, wprojT, x1, nullptr, c_bp, xf, xb,
            Tc, 384, 384, flag, nullptr);

        // ConvFFN branch
        ln_kernel<<<Tc / 4, 256, 0, stream>>>(x1, nullptr, c_g2, c_b2, ybuf, Tc,
                                              flag, 1);
        gemm_nt<1, false, false><<<GM * 12, 256, 0, stream>>>(
            ybuf, wfc1T, nullptr, hbuf, c_bf1, nullptr, nullptr,
            Tc, 1536, 384, nullptr, nullptr);
        dwconv_gelu<<<Tc, 192, 0, stream>>>(hbuf, c_wdwT, c_bdw, gbuf);
        gemm_nt<2, false, true><<<GM * 3, 256, 0, stream>>>(
            gbuf, wfc2T, of, ob, c_bf2, x1, nullptr,
            Tc, 384, 1536, nullptr, flag);
    }
}